// Round 8
// baseline (178.810 us; speedup 1.0000x reference)
//
#include <hip/hip_runtime.h>
#include <math.h>

typedef unsigned short u16;
typedef unsigned int u32;

#define NBATCH 16
#define NCH    256
#define NPIX   4096
#define NHEAD  4
#define HDIM   32
#define NMEM   4
#define HID    128
#define OC3    384
#define SCALE_Q 0.17677669529663687f

typedef __bf16 bf16x8 __attribute__((ext_vector_type(8)));
typedef float  f32x4  __attribute__((ext_vector_type(4)));

// native casts -> compiler emits v_cvt_pk_bf16_f32 (RNE)
__device__ __forceinline__ u16 bfb(float f){
  union { __bf16 h; u16 u; } x; x.h = (__bf16)f; return x.u;
}
__device__ __forceinline__ u32 pkbf2(float a, float b){
  union { __bf16 h[2]; u32 u; } x; x.h[0] = (__bf16)a; x.h[1] = (__bf16)b; return x.u;
}
// async global->LDS, 16B per lane (dest = uniform base + lane*16)
__device__ __forceinline__ void gload_lds16(const void* gp, void* lp){
  __builtin_amdgcn_global_load_lds(
      (const __attribute__((address_space(1))) unsigned int*)gp,
      (__attribute__((address_space(3))) unsigned int*)lp, 16, 0, 0);
}

// ---------------------------------------------------------------------------
// K0: pack wqb[o][c] = bf16(w_qkv*g_in), wob[c][e] = bf16(w_out);
//     + precompute memory-token ctx contribution (b-independent):
//       ctxmem[h][d][e] = sum_m exp(mk[h,d,m])*mv[h,e,m],
//       zmem[h][d]      = sum_m exp(mk[h,d,m])
// ---------------------------------------------------------------------------
__global__ __launch_bounds__(256) void k_pack(const float* __restrict__ wqkv,
                                              const float* __restrict__ gin,
                                              const float* __restrict__ wout,
                                              const float* __restrict__ memkv,
                                              u16* __restrict__ wqb,
                                              u16* __restrict__ wob,
                                              float* __restrict__ ctxmem,
                                              float* __restrict__ zmem)
{
  int i = blockIdx.x*256 + threadIdx.x;
  if (i < OC3*NCH){ int c = i & 255; wqb[i] = bfb(wqkv[i]*gin[c]); }
  else if (i < OC3*NCH + NCH*HID){ int j = i - OC3*NCH; wob[j] = bfb(wout[j]); }
  else {
    int j = i - (OC3*NCH + NCH*HID);
    if (j < 4096){
      int h = j>>10, d = (j>>5)&31, e = j&31;
      float s = 0.f;
      #pragma unroll
      for (int m=0;m<4;m++)
        s += __expf(memkv[(h*HDIM+d)*NMEM + m]) * memkv[512 + (h*HDIM+e)*NMEM + m];
      ctxmem[j] = s;
    } else if (j < 4224){
      int k = j - 4096; int h = k>>5, d = k&31;
      float s = 0.f;
      #pragma unroll
      for (int m=0;m<4;m++) s += __expf(memkv[(h*HDIM+d)*NMEM + m]);
      zmem[k] = s;
    }
  }
}

// ---------------------------------------------------------------------------
// K1 (FUSED, R6-proven): rms-norm + QKV GEMM + q-softmax + per-tile ctx
// partials (P + z) into ctxp2 slabs (plain vector stores, no atomics).
// ---------------------------------------------------------------------------
__global__ __launch_bounds__(512, 4) void k_qkvx(const float* __restrict__ x,
                                                 const u16* __restrict__ wqb,
                                                 u16* __restrict__ qt,
                                                 float* __restrict__ ctxp2)
{
  __shared__ __align__(16) char smem[52480];
  float (*Xs)[64]   = (float(*)[64])smem;               // 16384 B (phase-1 only)
  u16*   Bx         = (u16*)(smem + 16384);             // 64*264 u16 = 33792 B
  float (*ssqp)[64] = (float(*)[64])(smem + 50176);     // 2048 B
  float* rl         = (float*)(smem + 52224);           // 256 B
  // post-K-loop overlays (Xs and Bx are dead after the K-loop):
  u16*   Ek         = (u16*)smem;                       // 128*72 u16 = 18432 B
  u16*   Vv         = (u16*)(smem + 18432);             // 18432 B (ends 36864)
  float (*psx)[64]  = (float(*)[64])(smem + 36864);     // 2048 B

  const int t = threadIdx.x, w = t>>6, lane = t&63;
  const int n0 = blockIdx.x*64, b = blockIdx.y;
  const int qw = lane>>4, rr = lane&15;

  // phase 1: stage x via global_load_lds, pack bf16-transposed into Bx,
  // per-n sum-of-squares in fp32
  {
    float ssq = 0.f;
    for (int s=0;s<4;++s){
      asm volatile("s_waitcnt lgkmcnt(0)" ::: "memory");   // Xs reads of prev stage retired
      const float* gp = x + ((size_t)b*NCH + s*64 + w*8 + (lane>>4))*NPIX + n0 + (lane&15)*4;
      gload_lds16(gp,                    &Xs[w*8 + 0][0]);
      gload_lds16(gp + (size_t)4*NPIX,   &Xs[w*8 + 4][0]);
      asm volatile("s_waitcnt vmcnt(0)" ::: "memory");
      u32 pk[4];
      #pragma unroll
      for (int q=0;q<4;q++){
        float v0 = Xs[w*8 + 2*q    ][lane];
        float v1 = Xs[w*8 + 2*q + 1][lane];
        ssq += v0*v0 + v1*v1;
        pk[q] = pkbf2(v0, v1);
      }
      *(int4*)&Bx[lane*264 + s*64 + w*8] = make_int4((int)pk[0],(int)pk[1],(int)pk[2],(int)pk[3]);
    }
    ssqp[w][lane] = ssq;
  }
  __syncthreads();                                       // B1
  if (t < 64){
    float s = 0.f;
    #pragma unroll
    for (int g=0;g<8;g++) s += ssqp[g][t];
    rl[t] = 16.0f / fmaxf(sqrtf(s), 1e-12f);
  }

  f32x4 acc[3][4];
  #pragma unroll
  for (int p=0;p<3;p++)
    #pragma unroll
    for (int nf=0;nf<4;nf++) acc[p][nf] = (f32x4){0.f,0.f,0.f,0.f};

  // barrier-free K-loop: A-frags from global (L2) with 1-iter prefetch
  const u16* aw = wqb + (size_t)(w*16 + rr)*NCH + qw*8;
  bf16x8 caf0 = *(const bf16x8*)(aw);
  bf16x8 caf1 = *(const bf16x8*)(aw + 128*NCH);
  bf16x8 caf2 = *(const bf16x8*)(aw + 256*NCH);
  #pragma unroll
  for (int c0=0; c0<NCH; c0+=32){
    bf16x8 bfr[4];
    #pragma unroll
    for (int nf=0;nf<4;nf++)
      bfr[nf] = *(const bf16x8*)&Bx[(nf*16+rr)*264 + c0 + qw*8];
    bf16x8 naf0 = caf0, naf1 = caf1, naf2 = caf2;
    if (c0 < NCH-32){
      naf0 = *(const bf16x8*)(aw + c0+32);
      naf1 = *(const bf16x8*)(aw + 128*NCH + c0+32);
      naf2 = *(const bf16x8*)(aw + 256*NCH + c0+32);
    }
    #pragma unroll
    for (int nf=0;nf<4;nf++){
      acc[0][nf] = __builtin_amdgcn_mfma_f32_16x16x32_bf16(caf0, bfr[nf], acc[0][nf], 0, 0, 0); // q: D[o][n]
      acc[1][nf] = __builtin_amdgcn_mfma_f32_16x16x32_bf16(bfr[nf], caf1, acc[1][nf], 0, 0, 0); // k: D[n][o]
      acc[2][nf] = __builtin_amdgcn_mfma_f32_16x16x32_bf16(bfr[nf], caf2, acc[2][nf], 0, 0, 0); // v: D[n][o]
    }
    caf0 = naf0; caf1 = naf1; caf2 = naf2;
  }

  __syncthreads();   // B2: rl visible; Bx/Xs dead -> Ek/Vv/psx overlays usable

  // ---- ek / vv -> LDS [o][n] (stride 72), z[o] partial
  // swapped layout: o = w*16+rr ; n = nf*16+qw*4+reg
  float zk = 0.f;
  #pragma unroll
  for (int nf=0;nf<4;nf++){
    const float4 rv4 = *(const float4*)&rl[nf*16 + qw*4];
    float e0 = __expf(acc[1][nf][0]*rv4.x);
    float e1 = __expf(acc[1][nf][1]*rv4.y);
    float e2 = __expf(acc[1][nf][2]*rv4.z);
    float e3 = __expf(acc[1][nf][3]*rv4.w);
    zk += e0+e1+e2+e3;
    *(int2*)&Ek[(w*16+rr)*72 + nf*16 + qw*4] =
        make_int2((int)pkbf2(e0,e1), (int)pkbf2(e2,e3));
    float v0 = acc[2][nf][0]*rv4.x, v1 = acc[2][nf][1]*rv4.y;
    float v2 = acc[2][nf][2]*rv4.z, v3 = acc[2][nf][3]*rv4.w;
    *(int2*)&Vv[(w*16+rr)*72 + nf*16 + qw*4] =
        make_int2((int)pkbf2(v0,v1), (int)pkbf2(v2,v3));
  }
  zk += __shfl_xor(zk, 16, 64);
  zk += __shfl_xor(zk, 32, 64);

  // ---- q: rl-scale + softmax over head_dim (16 in-wave d + 16 partner)
  // normal layout: col = rr -> n = nf*16+rr ; row = qw*4+reg -> o = w*16+qw*4+reg
  float qv[4][4], pm[4], ps[4];
  #pragma unroll
  for (int nf=0;nf<4;nf++){
    float rv = rl[nf*16 + rr];
    float m = -1e30f;
    #pragma unroll
    for (int r=0;r<4;r++){ qv[nf][r] = acc[0][nf][r]*rv; m = fmaxf(m, qv[nf][r]); }
    m = fmaxf(m, __shfl_xor(m, 16, 64));
    m = fmaxf(m, __shfl_xor(m, 32, 64));
    float s = 0.f;
    #pragma unroll
    for (int r=0;r<4;r++){ qv[nf][r] = __expf(qv[nf][r]-m); s += qv[nf][r]; }
    s += __shfl_xor(s, 16, 64);
    s += __shfl_xor(s, 32, 64);
    pm[nf] = m; ps[nf] = s;
  }
  if (lane < 16){
    #pragma unroll
    for (int nf=0;nf<4;nf++){ ssqp[w][nf*16+lane] = pm[nf]; psx[w][nf*16+lane] = ps[nf]; }
  }
  __syncthreads();   // B3: partner partials + Ek/Vv visible
  {
    const int pw = w^1;   // waves (2h, 2h+1) share head h
    u16* qbase = qt + ((size_t)b*NPIX + n0)*HID + w*16 + qw*4;
    #pragma unroll
    for (int nf=0;nf<4;nf++){
      float om = ssqp[pw][nf*16+rr], os = psx[pw][nf*16+rr];
      float M = fmaxf(pm[nf], om);
      float S = ps[nf]*__expf(pm[nf]-M) + os*__expf(om-M);
      float f = __expf(pm[nf]-M) * SCALE_Q / S;
      u32 lo = pkbf2(qv[nf][0]*f, qv[nf][1]*f);
      u32 hi = pkbf2(qv[nf][2]*f, qv[nf][3]*f);
      *(int2*)(qbase + (size_t)(nf*16+rr)*HID) = make_int2((int)lo,(int)hi);
    }
  }

  // ---- ctx partial GEMM: wave w -> head h=w>>1, e-half eh=w&1
  // P[d][e] = sum_{n<64} ek[d,n]*vv[e,n]  via 16x16x32 MFMA (K = n)
  {
    const int h = w>>1, eh = w&1;
    f32x4 pacc[2] = {(f32x4){0.f,0.f,0.f,0.f},(f32x4){0.f,0.f,0.f,0.f}};
    #pragma unroll
    for (int ks=0; ks<2; ks++){
      bf16x8 bv = *(const bf16x8*)&Vv[(h*32+eh*16+rr)*72 + ks*32 + qw*8];
      #pragma unroll
      for (int i=0;i<2;i++){
        bf16x8 ae = *(const bf16x8*)&Ek[(h*32+i*16+rr)*72 + ks*32 + qw*8];
        pacc[i] = __builtin_amdgcn_mfma_f32_16x16x32_bf16(ae, bv, pacc[i], 0, 0, 0);
      }
    }
    // D layout: row (qw*4+reg) -> d-in-frag, col rr -> e-in-frag
    float* pb = ctxp2 + ((size_t)((b*64 + blockIdx.x)*4 + h))*1088;
    #pragma unroll
    for (int i=0;i<2;i++)
      #pragma unroll
      for (int reg=0;reg<4;reg++)
        pb[(i*16+qw*4+reg)*32 + eh*16 + rr] = pacc[i][reg];
    // z: o = w*16+rr -> h = w>>1 (same), d = (w&1)*16+rr
    if (qw==0) pb[1024 + (w&1)*16 + rr] = zk;
  }
}

// ---------------------------------------------------------------------------
// K2 (new): reduce partials + mem tokens -> normalized ctx, then FOLD through
// w_out: W2[b][c][h*32+d] = sum_e wob[c][h*32+e] * ctxn[b][h][d][e]  (bf16).
// One block per (b,h); 256 threads (4 waves).
// ---------------------------------------------------------------------------
__global__ __launch_bounds__(256) void k_w2(const float* __restrict__ ctxp2,
                                            const float* __restrict__ ctxmem,
                                            const float* __restrict__ zmem,
                                            const u16* __restrict__ wob,
                                            u16* __restrict__ w2b)
{
  __shared__ u16 Ct[32][40];      // ctxn bf16 [d][e], stride 40 (16B-aligned rows)
  __shared__ float zps[8][32];
  __shared__ float rinv[32];
  const int bh = blockIdx.x, b = bh>>2, h = bh&3;
  const int t = threadIdx.x, w = t>>6, lane = t&63;
  const int qw = lane>>4, rr = lane&15;
  const int d = t>>3, e0 = (t&7)*4;

  const float* base = ctxp2 + ((size_t)(b*64)*4 + h)*1088;
  // reduce P over the 64 n-tiles
  float4 ps = make_float4(0.f,0.f,0.f,0.f);
  for (int s=0;s<64;s++){
    float4 v = *(const float4*)(base + (size_t)s*4*1088 + d*32 + e0);
    ps.x+=v.x; ps.y+=v.y; ps.z+=v.z; ps.w+=v.w;
  }
  // reduce z (8 s-groups x 32 d)
  {
    int dz = t&31, sg = t>>5;
    float zp = 0.f;
    for (int s=sg*8; s<sg*8+8; s++) zp += base[(size_t)s*4*1088 + 1024 + dz];
    zps[sg][dz] = zp;
  }
  __syncthreads();
  if (t < 32){
    float z = zmem[h*32 + t];
    #pragma unroll
    for (int g=0;g<8;g++) z += zps[g][t];
    rinv[t] = 1.0f / z;
  }
  __syncthreads();
  // normalize + mem contribution -> bf16 Ct[d][e]
  {
    float ri = rinv[d];
    const float* cm = ctxmem + h*1024 + d*32 + e0;
    Ct[d][e0+0] = bfb((ps.x + cm[0])*ri);
    Ct[d][e0+1] = bfb((ps.y + cm[1])*ri);
    Ct[d][e0+2] = bfb((ps.z + cm[2])*ri);
    Ct[d][e0+3] = bfb((ps.w + cm[3])*ri);
  }
  __syncthreads();
  // W2 slice GEMM: [256 c x 32 d], K=32 (e). A = wob rows, B = Ct rows (d).
  f32x4 pacc[4][2];
  #pragma unroll
  for (int mf=0;mf<4;mf++)
    #pragma unroll
    for (int nd=0;nd<2;nd++) pacc[mf][nd] = (f32x4){0.f,0.f,0.f,0.f};
  bf16x8 be[2];
  be[0] = *(const bf16x8*)&Ct[rr][qw*8];
  be[1] = *(const bf16x8*)&Ct[16+rr][qw*8];
  #pragma unroll
  for (int mf=0;mf<4;mf++){
    bf16x8 af = *(const bf16x8*)&wob[(size_t)(w*64+mf*16+rr)*HID + h*32 + qw*8];
    #pragma unroll
    for (int nd=0;nd<2;nd++)
      pacc[mf][nd] = __builtin_amdgcn_mfma_f32_16x16x32_bf16(af, be[nd], pacc[mf][nd], 0, 0, 0);
  }
  // D: row (qw*4+reg) -> c-part, col rr -> d-part
  #pragma unroll
  for (int mf=0;mf<4;mf++)
    #pragma unroll
    for (int nd=0;nd<2;nd++)
      #pragma unroll
      for (int reg=0;reg<4;reg++)
        w2b[((size_t)b*NCH + w*64+mf*16+qw*4+reg)*HID + h*32 + nd*16 + rr] =
            bfb(pacc[mf][nd][reg]);
}

// ---------------------------------------------------------------------------
// K3 (rewritten): out = rms_c( W2b . q_hat + b_out ) * g_out.
// Single K=128 GEMM, swapped operands (mfma(q,w2)) so each lane holds 4
// consecutive n -> float4 stores. A/B frags DIRECT from global (L2/L3-hot).
// ---------------------------------------------------------------------------
__global__ __launch_bounds__(256) void k_fout(const u16* __restrict__ qt,
                                              const u16* __restrict__ w2b,
                                              const float* __restrict__ bout,
                                              const float* __restrict__ gout,
                                              float* __restrict__ out)
{
  __shared__ float ssql[4][64];
  const int t = threadIdx.x, w = t>>6, lane = t&63;
  const int n0 = blockIdx.x*64, b = blockIdx.y;
  const int qw = lane>>4, rr = lane&15;

  f32x4 acc[4][4];
  #pragma unroll
  for (int i=0;i<4;i++)
    #pragma unroll
    for (int j=0;j<4;j++) acc[i][j] = (f32x4){0.f,0.f,0.f,0.f};

  const u16* qbase = qt + ((size_t)b*NPIX + n0)*HID;
  const u16* wbase = w2b + (size_t)b*NCH*HID;
  #pragma unroll
  for (int k0=0;k0<HID;k0+=32){
    bf16x8 bq[4], aw[4];
    #pragma unroll
    for (int nf=0;nf<4;nf++)
      bq[nf] = *(const bf16x8*)(qbase + (size_t)(nf*16+rr)*HID + k0 + qw*8);
    #pragma unroll
    for (int mf=0;mf<4;mf++)
      aw[mf] = *(const bf16x8*)(wbase + (size_t)(w*64+mf*16+rr)*HID + k0 + qw*8);
    #pragma unroll
    for (int mf=0;mf<4;mf++)
      #pragma unroll
      for (int nf=0;nf<4;nf++)
        acc[mf][nf] = __builtin_amdgcn_mfma_f32_16x16x32_bf16(bq[nf], aw[mf], acc[mf][nf], 0, 0, 0);
  }
  // layout: c = w*64+mf*16+rr (col), n = nf*16+qw*4+reg (row)
  // bias + sum-of-squares over c
  float psq[4][4] = {{0.f}};
  #pragma unroll
  for (int mf=0;mf<4;mf++){
    float bb = bout[w*64+mf*16+rr];
    #pragma unroll
    for (int nf=0;nf<4;nf++)
      #pragma unroll
      for (int reg=0;reg<4;reg++){
        float v = acc[mf][nf][reg] + bb;
        acc[mf][nf][reg] = v;
        psq[nf][reg] += v*v;
      }
  }
  #pragma unroll
  for (int nf=0;nf<4;nf++)
    #pragma unroll
    for (int reg=0;reg<4;reg++){
      psq[nf][reg] += __shfl_xor(psq[nf][reg], 1, 64);
      psq[nf][reg] += __shfl_xor(psq[nf][reg], 2, 64);
      psq[nf][reg] += __shfl_xor(psq[nf][reg], 4, 64);
      psq[nf][reg] += __shfl_xor(psq[nf][reg], 8, 64);
    }
  if (rr==0){
    #pragma unroll
    for (int nf=0;nf<4;nf++)
      #pragma unroll
      for (int reg=0;reg<4;reg++)
        ssql[w][nf*16+qw*4+reg] = psq[nf][reg];
  }
  __syncthreads();
  float4 rv4[4];
  #pragma unroll
  for (int nf=0;nf<4;nf++){
    float4 s0 = *(const float4*)&ssql[0][nf*16+qw*4];
    float4 s1 = *(const float4*)&ssql[1][nf*16+qw*4];
    float4 s2 = *(const float4*)&ssql[2][nf*16+qw*4];
    float4 s3 = *(const float4*)&ssql[3][nf*16+qw*4];
    rv4[nf].x = 16.0f / fmaxf(sqrtf(s0.x+s1.x+s2.x+s3.x), 1e-12f);
    rv4[nf].y = 16.0f / fmaxf(sqrtf(s0.y+s1.y+s2.y+s3.y), 1e-12f);
    rv4[nf].z = 16.0f / fmaxf(sqrtf(s0.z+s1.z+s2.z+s3.z), 1e-12f);
    rv4[nf].w = 16.0f / fmaxf(sqrtf(s0.w+s1.w+s2.w+s3.w), 1e-12f);
  }
  #pragma unroll
  for (int mf=0;mf<4;mf++){
    float g = gout[w*64+mf*16+rr];
    float* po = out + ((size_t)(b*NCH + w*64+mf*16+rr))*NPIX + n0;
    #pragma unroll
    for (int nf=0;nf<4;nf++){
      float4 o4;
      o4.x = acc[mf][nf][0]*rv4[nf].x*g;
      o4.y = acc[mf][nf][1]*rv4[nf].y*g;
      o4.z = acc[mf][nf][2]*rv4[nf].z*g;
      o4.w = acc[mf][nf][3]*rv4[nf].w*g;
      *(float4*)(po + nf*16 + qw*4) = o4;
    }
  }
}

// ---------------------------------------------------------------------------
extern "C" void kernel_launch(void* const* d_in, const int* in_sizes, int n_in,
                              void* d_out, int out_size, void* d_ws, size_t ws_size,
                              hipStream_t stream)
{
  const float* x     = (const float*)d_in[0];
  const float* gin   = (const float*)d_in[1];
  const float* memkv = (const float*)d_in[2];
  const float* wqkv  = (const float*)d_in[3];
  const float* wout  = (const float*)d_in[4];
  const float* bout  = (const float*)d_in[5];
  const float* gout  = (const float*)d_in[6];
  float* out = (float*)d_out;

  char* ws = (char*)d_ws;
  u16*    qt     = (u16*)   (ws);                    // 16,777,216 ([b][n][o] bf16)
  float*  ctxp2  = (float*) (ws + 16777216);         // 17,825,792 (16*64*4*1088*4)
  u16*    w2b    = (u16*)   (ws + 34603008);         //  1,048,576 (16*256*128 bf16)
  float*  ctxmem = (float*) (ws + 35651584);         //     16,384
  float*  zmem   = (float*) (ws + 35667968);         //        512
  u16*    wqb    = (u16*)   (ws + 35668480);         //    196,608
  u16*    wob    = (u16*)   (ws + 35865088);         //     65,536 -> total 35,930,624

  hipLaunchKernelGGL(k_pack, dim3(529),   dim3(256), 0, stream,
                     wqkv, gin, wout, memkv, wqb, wob, ctxmem, zmem);
  hipLaunchKernelGGL(k_qkvx, dim3(64,16), dim3(512), 0, stream, x, wqb, qt, ctxp2);
  hipLaunchKernelGGL(k_w2,   dim3(64),    dim3(256), 0, stream,
                     ctxp2, ctxmem, zmem, wob, w2b);
  hipLaunchKernelGGL(k_fout, dim3(64,16), dim3(256), 0, stream,
                     qt, w2b, bout, gout, out);
}

// Round 10
// 172.872 us; speedup vs baseline: 1.0343x; 1.0343x over previous
//
#include <hip/hip_runtime.h>
#include <math.h>

typedef unsigned short u16;
typedef unsigned int u32;

#define NBATCH 16
#define NCH    256
#define NPIX   4096
#define NHEAD  4
#define HDIM   32
#define NMEM   4
#define HID    128
#define OC3    384
#define SCALE_Q 0.17677669529663687f

typedef __bf16 bf16x8 __attribute__((ext_vector_type(8)));
typedef float  f32x4  __attribute__((ext_vector_type(4)));

// native casts -> compiler emits v_cvt_pk_bf16_f32 (RNE)
__device__ __forceinline__ u16 bfb(float f){
  union { __bf16 h; u16 u; } x; x.h = (__bf16)f; return x.u;
}
__device__ __forceinline__ u32 pkbf2(float a, float b){
  union { __bf16 h[2]; u32 u; } x; x.h[0] = (__bf16)a; x.h[1] = (__bf16)b; return x.u;
}
// async global->LDS, 16B per lane (dest = uniform base + lane*16)
__device__ __forceinline__ void gload_lds16(const void* gp, void* lp){
  __builtin_amdgcn_global_load_lds(
      (const __attribute__((address_space(1))) unsigned int*)gp,
      (__attribute__((address_space(3))) unsigned int*)lp, 16, 0, 0);
}

// ---------------------------------------------------------------------------
// K0: pack wqb[o][c] = bf16(w_qkv*g_in), wob[c][e] = bf16(w_out);
//     + precompute memory-token ctx contribution (b-independent).
// ---------------------------------------------------------------------------
__global__ __launch_bounds__(256) void k_pack(const float* __restrict__ wqkv,
                                              const float* __restrict__ gin,
                                              const float* __restrict__ wout,
                                              const float* __restrict__ memkv,
                                              u16* __restrict__ wqb,
                                              u16* __restrict__ wob,
                                              float* __restrict__ ctxmem,
                                              float* __restrict__ zmem)
{
  int i = blockIdx.x*256 + threadIdx.x;
  if (i < OC3*NCH){ int c = i & 255; wqb[i] = bfb(wqkv[i]*gin[c]); }
  else if (i < OC3*NCH + NCH*HID){ int j = i - OC3*NCH; wob[j] = bfb(wout[j]); }
  else {
    int j = i - (OC3*NCH + NCH*HID);
    if (j < 4096){
      int h = j>>10, d = (j>>5)&31, e = j&31;
      float s = 0.f;
      #pragma unroll
      for (int m=0;m<4;m++)
        s += __expf(memkv[(h*HDIM+d)*NMEM + m]) * memkv[512 + (h*HDIM+e)*NMEM + m];
      ctxmem[j] = s;
    } else if (j < 4224){
      int k = j - 4096; int h = k>>5, d = k&31;
      float s = 0.f;
      #pragma unroll
      for (int m=0;m<4;m++) s += __expf(memkv[(h*HDIM+d)*NMEM + m]);
      zmem[k] = s;
    }
  }
}

// ---------------------------------------------------------------------------
// K1 (R6-proven): rms-norm + QKV GEMM + q-softmax + per-tile ctx partials
// (P + z) into ctxp2 slabs (plain vector stores).
// ---------------------------------------------------------------------------
__global__ __launch_bounds__(512, 4) void k_qkvx(const float* __restrict__ x,
                                                 const u16* __restrict__ wqb,
                                                 u16* __restrict__ qt,
                                                 float* __restrict__ ctxp2)
{
  __shared__ __align__(16) char smem[52480];
  float (*Xs)[64]   = (float(*)[64])smem;               // 16384 B (phase-1 only)
  u16*   Bx         = (u16*)(smem + 16384);             // 64*264 u16 = 33792 B
  float (*ssqp)[64] = (float(*)[64])(smem + 50176);     // 2048 B
  float* rl         = (float*)(smem + 52224);           // 256 B
  // post-K-loop overlays (Xs and Bx are dead after the K-loop):
  u16*   Ek         = (u16*)smem;                       // 128*72 u16 = 18432 B
  u16*   Vv         = (u16*)(smem + 18432);             // 18432 B (ends 36864)
  float (*psx)[64]  = (float(*)[64])(smem + 36864);     // 2048 B

  const int t = threadIdx.x, w = t>>6, lane = t&63;
  const int n0 = blockIdx.x*64, b = blockIdx.y;
  const int qw = lane>>4, rr = lane&15;

  // phase 1: stage x via global_load_lds, pack bf16-transposed into Bx,
  // per-n sum-of-squares in fp32
  {
    float ssq = 0.f;
    for (int s=0;s<4;++s){
      asm volatile("s_waitcnt lgkmcnt(0)" ::: "memory");
      const float* gp = x + ((size_t)b*NCH + s*64 + w*8 + (lane>>4))*NPIX + n0 + (lane&15)*4;
      gload_lds16(gp,                    &Xs[w*8 + 0][0]);
      gload_lds16(gp + (size_t)4*NPIX,   &Xs[w*8 + 4][0]);
      asm volatile("s_waitcnt vmcnt(0)" ::: "memory");
      u32 pk[4];
      #pragma unroll
      for (int q=0;q<4;q++){
        float v0 = Xs[w*8 + 2*q    ][lane];
        float v1 = Xs[w*8 + 2*q + 1][lane];
        ssq += v0*v0 + v1*v1;
        pk[q] = pkbf2(v0, v1);
      }
      *(int4*)&Bx[lane*264 + s*64 + w*8] = make_int4((int)pk[0],(int)pk[1],(int)pk[2],(int)pk[3]);
    }
    ssqp[w][lane] = ssq;
  }
  __syncthreads();                                       // B1
  if (t < 64){
    float s = 0.f;
    #pragma unroll
    for (int g=0;g<8;g++) s += ssqp[g][t];
    rl[t] = 16.0f / fmaxf(sqrtf(s), 1e-12f);
  }

  f32x4 acc[3][4];
  #pragma unroll
  for (int p=0;p<3;p++)
    #pragma unroll
    for (int nf=0;nf<4;nf++) acc[p][nf] = (f32x4){0.f,0.f,0.f,0.f};

  // barrier-free K-loop: A-frags from global (L2) with 1-iter prefetch
  const u16* aw = wqb + (size_t)(w*16 + rr)*NCH + qw*8;
  bf16x8 caf0 = *(const bf16x8*)(aw);
  bf16x8 caf1 = *(const bf16x8*)(aw + 128*NCH);
  bf16x8 caf2 = *(const bf16x8*)(aw + 256*NCH);
  #pragma unroll
  for (int c0=0; c0<NCH; c0+=32){
    bf16x8 bfr[4];
    #pragma unroll
    for (int nf=0;nf<4;nf++)
      bfr[nf] = *(const bf16x8*)&Bx[(nf*16+rr)*264 + c0 + qw*8];
    bf16x8 naf0 = caf0, naf1 = caf1, naf2 = caf2;
    if (c0 < NCH-32){
      naf0 = *(const bf16x8*)(aw + c0+32);
      naf1 = *(const bf16x8*)(aw + 128*NCH + c0+32);
      naf2 = *(const bf16x8*)(aw + 256*NCH + c0+32);
    }
    #pragma unroll
    for (int nf=0;nf<4;nf++){
      acc[0][nf] = __builtin_amdgcn_mfma_f32_16x16x32_bf16(caf0, bfr[nf], acc[0][nf], 0, 0, 0); // q: D[o][n]
      acc[1][nf] = __builtin_amdgcn_mfma_f32_16x16x32_bf16(bfr[nf], caf1, acc[1][nf], 0, 0, 0); // k: D[n][o]
      acc[2][nf] = __builtin_amdgcn_mfma_f32_16x16x32_bf16(bfr[nf], caf2, acc[2][nf], 0, 0, 0); // v: D[n][o]
    }
    caf0 = naf0; caf1 = naf1; caf2 = naf2;
  }

  __syncthreads();   // B2: rl visible; Bx/Xs dead -> Ek/Vv/psx overlays usable

  // ek / vv -> LDS [o][n] (stride 72), z[o] partial
  float zk = 0.f;
  #pragma unroll
  for (int nf=0;nf<4;nf++){
    const float4 rv4 = *(const float4*)&rl[nf*16 + qw*4];
    float e0 = __expf(acc[1][nf][0]*rv4.x);
    float e1 = __expf(acc[1][nf][1]*rv4.y);
    float e2 = __expf(acc[1][nf][2]*rv4.z);
    float e3 = __expf(acc[1][nf][3]*rv4.w);
    zk += e0+e1+e2+e3;
    *(int2*)&Ek[(w*16+rr)*72 + nf*16 + qw*4] =
        make_int2((int)pkbf2(e0,e1), (int)pkbf2(e2,e3));
    float v0 = acc[2][nf][0]*rv4.x, v1 = acc[2][nf][1]*rv4.y;
    float v2 = acc[2][nf][2]*rv4.z, v3 = acc[2][nf][3]*rv4.w;
    *(int2*)&Vv[(w*16+rr)*72 + nf*16 + qw*4] =
        make_int2((int)pkbf2(v0,v1), (int)pkbf2(v2,v3));
  }
  zk += __shfl_xor(zk, 16, 64);
  zk += __shfl_xor(zk, 32, 64);

  // q: rl-scale + softmax over head_dim (16 in-wave d + 16 partner)
  float qv[4][4], pm[4], ps[4];
  #pragma unroll
  for (int nf=0;nf<4;nf++){
    float rv = rl[nf*16 + rr];
    float m = -1e30f;
    #pragma unroll
    for (int r=0;r<4;r++){ qv[nf][r] = acc[0][nf][r]*rv; m = fmaxf(m, qv[nf][r]); }
    m = fmaxf(m, __shfl_xor(m, 16, 64));
    m = fmaxf(m, __shfl_xor(m, 32, 64));
    float s = 0.f;
    #pragma unroll
    for (int r=0;r<4;r++){ qv[nf][r] = __expf(qv[nf][r]-m); s += qv[nf][r]; }
    s += __shfl_xor(s, 16, 64);
    s += __shfl_xor(s, 32, 64);
    pm[nf] = m; ps[nf] = s;
  }
  if (lane < 16){
    #pragma unroll
    for (int nf=0;nf<4;nf++){ ssqp[w][nf*16+lane] = pm[nf]; psx[w][nf*16+lane] = ps[nf]; }
  }
  __syncthreads();   // B3: partner partials + Ek/Vv visible
  {
    const int pw = w^1;   // waves (2h, 2h+1) share head h
    u16* qbase = qt + ((size_t)b*NPIX + n0)*HID + w*16 + qw*4;
    #pragma unroll
    for (int nf=0;nf<4;nf++){
      float om = ssqp[pw][nf*16+rr], os = psx[pw][nf*16+rr];
      float M = fmaxf(pm[nf], om);
      float S = ps[nf]*__expf(pm[nf]-M) + os*__expf(om-M);
      float f = __expf(pm[nf]-M) * SCALE_Q / S;
      u32 lo = pkbf2(qv[nf][0]*f, qv[nf][1]*f);
      u32 hi = pkbf2(qv[nf][2]*f, qv[nf][3]*f);
      *(int2*)(qbase + (size_t)(nf*16+rr)*HID) = make_int2((int)lo,(int)hi);
    }
  }

  // ctx partial GEMM: wave w -> head h=w>>1, e-half eh=w&1
  {
    const int h = w>>1, eh = w&1;
    f32x4 pacc[2] = {(f32x4){0.f,0.f,0.f,0.f},(f32x4){0.f,0.f,0.f,0.f}};
    #pragma unroll
    for (int ks=0; ks<2; ks++){
      bf16x8 bv = *(const bf16x8*)&Vv[(h*32+eh*16+rr)*72 + ks*32 + qw*8];
      #pragma unroll
      for (int i=0;i<2;i++){
        bf16x8 ae = *(const bf16x8*)&Ek[(h*32+i*16+rr)*72 + ks*32 + qw*8];
        pacc[i] = __builtin_amdgcn_mfma_f32_16x16x32_bf16(ae, bv, pacc[i], 0, 0, 0);
      }
    }
    float* pb = ctxp2 + ((size_t)((b*64 + blockIdx.x)*4 + h))*1088;
    #pragma unroll
    for (int i=0;i<2;i++)
      #pragma unroll
      for (int reg=0;reg<4;reg++)
        pb[(i*16+qw*4+reg)*32 + eh*16 + rr] = pacc[i][reg];
    if (qw==0) pb[1024 + (w&1)*16 + rr] = zk;
  }
}

// ---------------------------------------------------------------------------
// K2 (NEW): parallel split-K reduce of ctxp2 slabs -> ctxa/za via atomics.
// 256 blocks (4 per (b,h)), each sums 16 slabs with fully-unrolled
// independent float4 loads (high MLP), then 4 atomicAdds/thread
// (4-way contention only). Replaces the serial 64-iter k_fin (~25-30us).
// ---------------------------------------------------------------------------
__global__ __launch_bounds__(256) void k_red(const float* __restrict__ ctxp2,
                                             float* __restrict__ ctxa,
                                             float* __restrict__ za)
{
  const int r = blockIdx.x;            // 0..255
  const int b = r>>4, h = (r>>2)&3, g = r&3;
  const int t = threadIdx.x;
  const int d = t>>3, e0 = (t&7)*4;
  const float* base = ctxp2 + ((size_t)((b*64 + g*16)*4) + h)*1088;
  float4 sum = make_float4(0.f,0.f,0.f,0.f);
  #pragma unroll
  for (int s=0;s<16;s++){
    float4 v = *(const float4*)(base + (size_t)s*4*1088 + d*32 + e0);
    sum.x+=v.x; sum.y+=v.y; sum.z+=v.z; sum.w+=v.w;
  }
  float* pa = ctxa + (size_t)b*4096 + h*1024 + d*32 + e0;
  atomicAdd(pa+0, sum.x); atomicAdd(pa+1, sum.y);
  atomicAdd(pa+2, sum.z); atomicAdd(pa+3, sum.w);
  if (t < 32){
    float zs = 0.f;
    #pragma unroll
    for (int s=0;s<16;s++) zs += base[(size_t)s*4*1088 + 1024 + t];
    atomicAdd(&za[b*128 + h*32 + t], zs);
  }
}

// ---------------------------------------------------------------------------
// K3 (R7-proven): stage ctx = (ctxa+ctxmem)/(za+zmem) -> Cb bf16 [h][e][d];
// PV MFMA (q direct from qt[b][n][o]); w_out GEMM; rms; store.
// ---------------------------------------------------------------------------
__global__ __launch_bounds__(256) void k_fout(const u16* __restrict__ qt,
                                              const float* __restrict__ ctxa,
                                              const float* __restrict__ za,
                                              const float* __restrict__ ctxmem,
                                              const float* __restrict__ zmem,
                                              const u16* __restrict__ wob,
                                              const float* __restrict__ bout,
                                              const float* __restrict__ gout,
                                              float* __restrict__ out)
{
  __shared__ u16 Cb[4*32*40];     // [h][e][d], stride 40
  __shared__ u16 Ao[64*136];      // [n][e(hid)]
  __shared__ float ssql[4][64];
  const int t = threadIdx.x, w = t>>6, lane = t&63;
  const int n0 = blockIdx.x*64, b = blockIdx.y;
  const int qw = lane>>4, rr = lane&15;

  // stage normalized ctx -> Cb bf16 transposed [h][e][d]
  {
    const int d = (t>>3)&31, e0 = (t&7)*4;
    #pragma unroll
    for (int h=0;h<4;h++){
      float4 a = *(const float4*)(ctxa + (size_t)b*4096 + h*1024 + d*32 + e0);
      float4 m = *(const float4*)(ctxmem + h*1024 + d*32 + e0);
      float rinv = 1.0f / (za[b*128 + h*32 + d] + zmem[h*32 + d]);
      Cb[(h*32+e0+0)*40 + d] = bfb((a.x+m.x)*rinv);
      Cb[(h*32+e0+1)*40 + d] = bfb((a.y+m.y)*rinv);
      Cb[(h*32+e0+2)*40 + d] = bfb((a.z+m.z)*rinv);
      Cb[(h*32+e0+3)*40 + d] = bfb((a.w+m.w)*rinv);
    }
  }
  __syncthreads();

  // PV MFMA: wave w owns n-frag w (n = w*16 + rr); q direct from qt[b][n][o]
  f32x4 pv[4][2];
  const u16* qp = qt + ((size_t)b*NPIX + n0 + w*16 + rr)*HID;
  #pragma unroll
  for (int h=0;h<4;h++){
    bf16x8 bq = *(const bf16x8*)(qp + h*32 + qw*8);
    #pragma unroll
    for (int ef=0;ef<2;ef++){
      bf16x8 af = *(const bf16x8*)&Cb[(h*32 + ef*16 + rr)*40 + qw*8];
      f32x4 z = (f32x4){0.f,0.f,0.f,0.f};
      pv[h][ef] = __builtin_amdgcn_mfma_f32_16x16x32_bf16(af, bq, z, 0, 0, 0);
    }
  }
  // write ao -> Ao[n][e]
  #pragma unroll
  for (int h=0;h<4;h++)
    #pragma unroll
    for (int ef=0;ef<2;ef++){
      u32 lohi0 = pkbf2(pv[h][ef][0], pv[h][ef][1]);
      u32 lohi1 = pkbf2(pv[h][ef][2], pv[h][ef][3]);
      *(int2*)&Ao[(w*16+rr)*136 + h*32 + ef*16 + qw*4] = make_int2((int)lohi0,(int)lohi1);
    }
  __syncthreads();

  // w_out GEMM: K=128 over e; A = wob[c][e] direct from global (L2-hot)
  f32x4 acc[4][4];
  #pragma unroll
  for (int i=0;i<4;i++)
    #pragma unroll
    for (int j=0;j<4;j++) acc[i][j] = (f32x4){0.f,0.f,0.f,0.f};
  #pragma unroll
  for (int k0=0; k0<HID; k0+=32){
    bf16x8 af[4], bfr[4];
    #pragma unroll
    for (int mf=0;mf<4;mf++)
      af[mf] = *(const bf16x8*)&wob[(size_t)(w*64 + mf*16 + rr)*HID + k0 + qw*8];
    #pragma unroll
    for (int nf=0;nf<4;nf++)
      bfr[nf] = *(const bf16x8*)&Ao[(nf*16+rr)*136 + k0 + qw*8];
    #pragma unroll
    for (int mf=0;mf<4;mf++)
      #pragma unroll
      for (int nf=0;nf<4;nf++)
        acc[mf][nf] = __builtin_amdgcn_mfma_f32_16x16x32_bf16(af[mf], bfr[nf], acc[mf][nf], 0, 0, 0);
  }
  // bias + column sum-of-squares (full 256 c in this block)
  float pssq[4] = {0.f,0.f,0.f,0.f};
  #pragma unroll
  for (int mf=0;mf<4;mf++)
    #pragma unroll
    for (int reg=0;reg<4;reg++){
      int c = w*64 + mf*16 + qw*4 + reg;
      float bb = bout[c];
      #pragma unroll
      for (int nf=0;nf<4;nf++){
        float v = acc[mf][nf][reg] + bb;
        acc[mf][nf][reg] = v;
        pssq[nf] += v*v;
      }
    }
  #pragma unroll
  for (int nf=0;nf<4;nf++){
    pssq[nf] += __shfl_xor(pssq[nf], 16, 64);
    pssq[nf] += __shfl_xor(pssq[nf], 32, 64);
  }
  if (qw==0){
    #pragma unroll
    for (int nf=0;nf<4;nf++) ssql[w][nf*16+rr] = pssq[nf];
  }
  __syncthreads();
  float rv[4];
  #pragma unroll
  for (int nf=0;nf<4;nf++){
    int col = nf*16 + rr;
    float sm = ssql[0][col]+ssql[1][col]+ssql[2][col]+ssql[3][col];
    rv[nf] = 16.0f / fmaxf(sqrtf(sm), 1e-12f);
  }
  #pragma unroll
  for (int mf=0;mf<4;mf++)
    #pragma unroll
    for (int reg=0;reg<4;reg++){
      int c = w*64 + mf*16 + qw*4 + reg;
      float g = gout[c];
      float* po = out + ((size_t)(b*NCH + c))*NPIX + n0;
      #pragma unroll
      for (int nf=0;nf<4;nf++)
        po[nf*16 + rr] = acc[mf][nf][reg]*rv[nf]*g;
    }
}

// ---------------------------------------------------------------------------
extern "C" void kernel_launch(void* const* d_in, const int* in_sizes, int n_in,
                              void* d_out, int out_size, void* d_ws, size_t ws_size,
                              hipStream_t stream)
{
  const float* x     = (const float*)d_in[0];
  const float* gin   = (const float*)d_in[1];
  const float* memkv = (const float*)d_in[2];
  const float* wqkv  = (const float*)d_in[3];
  const float* wout  = (const float*)d_in[4];
  const float* bout  = (const float*)d_in[5];
  const float* gout  = (const float*)d_in[6];
  float* out = (float*)d_out;

  char* ws = (char*)d_ws;
  u16*    qt     = (u16*)   (ws);                    // 16,777,216 ([b][n][o] bf16)
  float*  ctxp2  = (float*) (ws + 16777216);         // 17,825,792 (16*64*4*1088*4)
  float*  ctxa   = (float*) (ws + 34603008);         //    262,144
  float*  za     = (float*) (ws + 34865152);         //      8,192
  float*  ctxmem = (float*) (ws + 34873344);         //     16,384
  float*  zmem   = (float*) (ws + 34889728);         //        512
  u16*    wqb    = (u16*)   (ws + 34890240);         //    196,608
  u16*    wob    = (u16*)   (ws + 35086848);         //     65,536 -> total 35,152,384

  // zero the split-K accumulators (ctxa + za contiguous: 270,336 B)
  hipMemsetAsync(ws + 34603008, 0, 270336, stream);

  hipLaunchKernelGGL(k_pack, dim3(529),   dim3(256), 0, stream,
                     wqkv, gin, wout, memkv, wqb, wob, ctxmem, zmem);
  hipLaunchKernelGGL(k_qkvx, dim3(64,16), dim3(512), 0, stream, x, wqb, qt, ctxp2);
  hipLaunchKernelGGL(k_red,  dim3(256),   dim3(256), 0, stream, ctxp2, ctxa, za);
  hipLaunchKernelGGL(k_fout, dim3(64,16), dim3(256), 0, stream,
                     qt, ctxa, za, ctxmem, zmem, wob, bout, gout, out);
}